// Round 14
// baseline (598.255 us; speedup 1.0000x reference)
//
#include <hip/hip_runtime.h>

typedef unsigned int uint;
typedef unsigned short ushort;
typedef _Float16 f16;
typedef _Float16 h8 __attribute__((ext_vector_type(8)));
typedef float f32x4 __attribute__((ext_vector_type(4)));

// B=16 L=512 H=12 d=64 D=768 N3=2304 C=20 M=8192

__device__ __forceinline__ float b2f(ushort u){ return __uint_as_float(((uint)u)<<16); }
__device__ __forceinline__ ushort f2b(float f){
  uint u = __float_as_uint(f);
  uint r = u + 0x7fffu + ((u>>16)&1u);
  return (ushort)(r>>16);
}
__device__ __forceinline__ float leaky(float x){ return x >= 0.f ? x : 0.01f*x; }
__device__ __forceinline__ float ldf(const void* p, int idx, int isb){
  return isb ? b2f(((const ushort*)p)[idx]) : ((const float*)p)[idx];
}
__device__ __forceinline__ float4 ldf4(const void* p, int idx, int isb){
  if (isb){
    ushort4 u = ((const ushort4*)p)[idx>>2];   // idx multiple of 4 -> 8B aligned
    return make_float4(b2f(u.x), b2f(u.y), b2f(u.z), b2f(u.w));
  }
  return ((const float4*)p)[idx>>2];           // 16B aligned
}

#define GLOAD16(gp, lp) __builtin_amdgcn_global_load_lds( \
    (const __attribute__((address_space(1))) void*)(gp), \
    (__attribute__((address_space(3))) void*)(lp), 16, 0, 0)

// ---------- K_init: detect dtype (block 0) + zero colsum0/1 (blocks 1..64) ----------
__global__ __launch_bounds__(256) void k_init(const ushort* __restrict__ wvbits,
    int* __restrict__ flag, float* __restrict__ zbase){
  int bid = blockIdx.x, tid = threadIdx.x;
  if (bid == 0){
    if (tid == 0){
      int sane = 0;
      for (int i=0;i<128;i++){
        uint e = (wvbits[i]>>7)&0xffu;
        if (e==0u || (e>=90u && e<=150u)) sane++;
      }
      *flag = (sane >= 115) ? 1 : 0;
    }
  } else {
    zbase[(bid-1)*256 + tid] = 0.f;   // 64*256 = 16384 floats (colsum0+colsum1)
  }
}

// ---------- K_prep_all: build_x + up to 3 repacks, range-dispatched on blockIdx.x ----------
__global__ __launch_bounds__(256) void k_prep_all(const int* __restrict__ ids,
    const void* __restrict__ emb, const void* __restrict__ wv,
    const void* __restrict__ W0, const void* __restrict__ W1,
    const int* __restrict__ flag,
    f16* __restrict__ AhA, f16* __restrict__ WhA,
    f16* __restrict__ AhB, f16* __restrict__ WhB,
    int nBX, int nW0, int nA1, int nW1){
  int isb = *flag;
  int bx = blockIdx.x, tid = threadIdx.x;
  if (bx < nBX){
    int t = bx*256 + tid;            // 8192*96 units
    int m = t / 96, kk = (t % 96) * 8;
    float o[8];
    if (isb){
      const ushort* src = (const ushort*)emb + (size_t)ids[m]*768 + kk;
      uint4 v = *(const uint4*)src;
      o[0]=__uint_as_float((v.x&0xffffu)<<16); o[1]=__uint_as_float(v.x&0xffff0000u);
      o[2]=__uint_as_float((v.y&0xffffu)<<16); o[3]=__uint_as_float(v.y&0xffff0000u);
      o[4]=__uint_as_float((v.z&0xffffu)<<16); o[5]=__uint_as_float(v.z&0xffff0000u);
      o[6]=__uint_as_float((v.w&0xffffu)<<16); o[7]=__uint_as_float(v.w&0xffff0000u);
    } else {
      const float* src = (const float*)emb + (size_t)ids[m]*768 + kk;
      float4 v0 = ((const float4*)src)[0];
      float4 v1 = ((const float4*)src)[1];
      o[0]=v0.x; o[1]=v0.y; o[2]=v0.z; o[3]=v0.w;
      o[4]=v1.x; o[5]=v1.y; o[6]=v1.z; o[7]=v1.w;
    }
    h8 hv;
    #pragma unroll
    for (int i=0;i<8;i++) hv[i] = (f16)leaky(o[i]);
    *(h8*)(AhA + (size_t)m*768 + kk) = hv;
  } else if (bx < nBX + nW0){
    int t = (bx - nBX)*256 + tid;    // 2304*96 units
    int n = t / 96, kk = (t % 96) * 8;
    h8 hv;
    #pragma unroll
    for (int i=0;i<8;i++) hv[i] = (f16)ldf(W0, n*768 + kk + i, isb);
    *(h8*)(WhA + (size_t)n*768 + kk) = hv;
  } else if (bx < nBX + nW0 + nA1){
    int t = (bx - nBX - nW0)*256 + tid;  // 8192*40 units
    int n = t / 40, kk = (t % 40) * 8;
    h8 hv;
    #pragma unroll
    for (int i=0;i<8;i++){
      int k = kk + i;
      hv[i] = (k < 300) ? (f16)ldf(wv, n*300 + k, isb) : (f16)0.f;
    }
    *(h8*)(AhB + (size_t)n*320 + kk) = hv;
  } else {
    int t = (bx - nBX - nW0 - nA1)*256 + tid;  // 2304*40 units
    int n = t / 40, kk = (t % 40) * 8;
    h8 hv;
    #pragma unroll
    for (int i=0;i<8;i++){
      int k = kk + i;
      hv[i] = (k < 300) ? (f16)ldf(W1, n*300 + k, isb) : (f16)0.f;
    }
    *(h8*)(WhB + (size_t)n*320 + kk) = hv;
  }
}

// ---------- K1: merged MFMA QKV GEMM (branch by blockIdx.z), m97 LDS staging, fused QK-norm ----------
// Epilogue: wave-private LDS transpose (reuses staging buffer after sync) -> 8 coalesced h8
// stores per thread (1KB dense per wave-instr) instead of 64 scalar scattered f16 stores.
__global__ __launch_bounds__(256) void k_gemm_m(
    const f16* AhA, const f16* WhA, const void* biasA, int KA,
    f16* QhA, f16* KhA, f16* VtA,
    const f16* AhB, const f16* WhB, const void* biasB, int KB,
    f16* QhB, f16* KhB, f16* VtB,
    const int* __restrict__ flag, int sbase){
  __shared__ __align__(16) f16 SB[2*128*64];
  f16* As = SB;
  f16* Bs = SB + 128*64;
  int z = sbase + blockIdx.z;
  const f16* Ah = z ? AhB : AhA;
  const f16* Wh = z ? WhB : WhA;
  const void* bias = z ? biasB : biasA;
  int KP = z ? KB : KA;
  f16* Qh = z ? QhB : QhA;
  f16* Kh = z ? KhB : KhA;
  f16* Vt = z ? VtB : VtA;
  int STEPS = KP >> 6;

  int tid = threadIdx.x;
  int w = tid >> 6, lane = tid & 63;
  int mrow = lane & 15, kq = lane >> 4;
  int m0 = (((blockIdx.x & 7)<<3) | (blockIdx.x >> 3)) * 128;   // XCD-chunked (64%8==0)
  int n0 = blockIdx.y * 128;
  int msub = (w & 1) * 64, nsub = (w >> 1) * 64;

  f32x4 acc[4][4];
  #pragma unroll
  for (int mt=0; mt<4; mt++)
    #pragma unroll
    for (int nt=0; nt<4; nt++) acc[mt][nt] = (f32x4){0.f,0.f,0.f,0.f};

  int cbase = w*64 + lane;

  for (int step=0; step<STEPS; step++){
    int k0 = step*64;
    __syncthreads();
    #pragma unroll
    for (int rep=0; rep<4; rep++){
      int cb = rep*256 + w*64;
      int c  = rep*256 + cbase;
      int row = c >> 3;
      int qs  = (c & 7) ^ (row & 7);
      GLOAD16(Ah + (size_t)(m0+row)*KP + k0 + qs*8, As + cb*8);
      GLOAD16(Wh + (size_t)(n0+row)*KP + k0 + qs*8, Bs + cb*8);
    }
    __syncthreads();
    #pragma unroll
    for (int ks=0; ks<2; ks++){
      h8 af[4], bf[4];
      #pragma unroll
      for (int mt=0; mt<4; mt++){
        int row = msub + mt*16 + mrow;
        int slot = (ks*4 + kq) ^ (row & 7);
        af[mt] = *(const h8*)(As + row*64 + slot*8);
      }
      #pragma unroll
      for (int nt=0; nt<4; nt++){
        int row = nsub + nt*16 + mrow;
        int slot = (ks*4 + kq) ^ (row & 7);
        bf[nt] = *(const h8*)(Bs + row*64 + slot*8);
      }
      #pragma unroll
      for (int mt=0; mt<4; mt++)
        #pragma unroll
        for (int nt=0; nt<4; nt++)
          acc[mt][nt] = __builtin_amdgcn_mfma_f32_16x16x32_f16(af[mt], bf[nt], acc[mt][nt], 0, 0, 0);
    }
  }

  int isb = *flag;
  int n0w = n0 + nsub;
  int s = n0w / 768;
  int h = (n0w % 768) >> 6;
  float bv[4];
  #pragma unroll
  for (int nt=0; nt<4; nt++) bv[nt] = ldf(bias, n0w + nt*16 + mrow, isb);

  __syncthreads();                      // all MFMA reads of As/Bs done; reuse as transpose tile
  f16* tw = SB + w*4096;                // wave-private 64x64 f16 tile (8KB)

  #pragma unroll
  for (int mt=0; mt<4; mt++){
    float yv[4][4];
    #pragma unroll
    for (int nt=0; nt<4; nt++)
      #pragma unroll
      for (int r=0; r<4; r++)
        yv[nt][r] = leaky(acc[mt][nt][r] + bv[nt]);
    if (s < 2){
      #pragma unroll
      for (int r=0; r<4; r++){
        float ss = yv[0][r]*yv[0][r] + yv[1][r]*yv[1][r]
                 + yv[2][r]*yv[2][r] + yv[3][r]*yv[3][r];
        ss += __shfl_xor(ss, 1); ss += __shfl_xor(ss, 2);
        ss += __shfl_xor(ss, 4); ss += __shfl_xor(ss, 8);
        float rn = 1.f / fmaxf(sqrtf(ss), 1e-8f);
        #pragma unroll
        for (int nt=0; nt<4; nt++) yv[nt][r] *= rn;
      }
    }
    #pragma unroll
    for (int nt=0; nt<4; nt++){
      #pragma unroll
      for (int r=0; r<4; r++){
        int ml = mt*16 + kq*4 + r;      // local row in quadrant
        int dd = nt*16 + mrow;          // local col (d-index)
        if (s == 2) tw[dd*64 + (ml ^ ((dd&7)<<3))] = (f16)yv[nt][r];
        else        tw[ml*64 + (dd ^ ((ml&7)<<3))] = (f16)yv[nt][r];
      }
    }
  }
  // wave-private tile: in-wave lgkmcnt ordering suffices, no barrier

  int mq = m0 + msub;                   // quadrant base row (64-aligned, within one 512-block)
  int bq = mq >> 9, l0 = mq & 511;
  if (s < 2){
    f16* gb = (s == 0 ? Qh : Kh) + ((size_t)(bq*12 + h)*512 + l0)*64;
    #pragma unroll
    for (int ps=0; ps<8; ps++){
      int ml = ps*8 + (lane>>3);
      int d0 = (lane&7)*8;
      h8 v = *(const h8*)(tw + ml*64 + (d0 ^ ((ml&7)<<3)));
      *(h8*)(gb + (size_t)ml*64 + d0) = v;    // 8 rows x 128B dense per wave-instr
    }
  } else {
    f16* gb = Vt + ((size_t)(bq*12 + h)*64)*512 + l0;
    #pragma unroll
    for (int ps=0; ps<8; ps++){
      int dd = ps*8 + (lane>>3);
      int m8 = (lane&7)*8;
      h8 v = *(const h8*)(tw + dd*64 + (m8 ^ ((dd&7)<<3)));
      *(h8*)(gb + (size_t)dd*512 + m8) = v;   // 8 dd-rows x 128B dense per wave-instr
    }
  }
}

// ---------- K3a: scores -> head-LN -> exp -> E (fp16) + rowsum PARTIALS (r9 proven body) ----------
__global__ __launch_bounds__(256) void k_scores(const f16* __restrict__ Qh,
    const f16* __restrict__ Kh, const void* __restrict__ gamma,
    const void* __restrict__ beta, const int* __restrict__ flag,
    f16* __restrict__ E, float* __restrict__ lsump){
  constexpr int TS = 72;
  __shared__ f16 S[12*16*TS];
  __shared__ float gL[12], beL[12];

  int tid = threadIdx.x;
  int w = tid >> 6, lane = tid & 63;
  int kq = lane >> 4, mrow = lane & 15;
  int bx = (blockIdx.x & 7)*512 + (blockIdx.x >> 3);   // XCD-chunked (4096%8==0, bijective)
  int jt = bx & 7, it = (bx >> 3) & 31, b = bx >> 8;
  int i0 = it*16, j0 = jt*64;

  if (tid < 12){ int isb = *flag; gL[tid] = ldf(gamma, tid, isb); beL[tid] = ldf(beta, tid, isb); }

  #pragma unroll
  for (int hh=0; hh<3; hh++){
    int h = w*3 + hh;
    const f16* kb = Kh + ((size_t)(b*12+h)*512 + i0 + mrow)*64;
    h8 a0 = *(const h8*)(kb + kq*8);
    h8 a1 = *(const h8*)(kb + 32 + kq*8);
    const f16* qb = Qh + ((size_t)(b*12+h)*512 + j0)*64;
    #pragma unroll
    for (int jn=0; jn<4; jn++){
      const f16* qr = qb + (size_t)(jn*16 + mrow)*64;
      h8 q0 = *(const h8*)(qr + kq*8);
      h8 q1 = *(const h8*)(qr + 32 + kq*8);
      f32x4 c = (f32x4){0.f,0.f,0.f,0.f};
      c = __builtin_amdgcn_mfma_f32_16x16x32_f16(a0, q0, c, 0, 0, 0);
      c = __builtin_amdgcn_mfma_f32_16x16x32_f16(a1, q1, c, 0, 0, 0);
      #pragma unroll
      for (int r=0;r<4;r++)
        S[(h*16 + kq*4 + r)*TS + jn*16 + mrow] = (f16)c[r];
    }
  }
  __syncthreads();
  int pj = tid & 63, piw = tid >> 6;
  #pragma unroll
  for (int p=0; p<4; p++){
    int i = piw*4 + p;
    float s[12];
    float mu = 0.f, sq = 0.f;
    #pragma unroll
    for (int h=0;h<12;h++){ s[h] = (float)S[(h*16+i)*TS + pj]; mu += s[h]; sq += s[h]*s[h]; }
    mu *= (1.f/12.f);
    float var = fmaxf(sq*(1.f/12.f) - mu*mu, 0.f);
    float rstd = rsqrtf(var + 1e-5f);
    #pragma unroll
    for (int h=0;h<12;h++){
      float e = __expf((s[h]-mu)*rstd*gL[h] + beL[h]);
      S[(h*16+i)*TS + pj] = (f16)e;
    }
  }
  __syncthreads();
  if (tid < 192){
    int h = tid >> 4, i = tid & 15;
    const f16* zr = &S[(h*16 + i)*TS];
    float ssum = 0.f;
    #pragma unroll
    for (int q=0;q<8;q++){
      h8 v = *(const h8*)(zr + q*8);
      #pragma unroll
      for (int t=0;t<8;t++) ssum += (float)v[t];
    }
    lsump[((size_t)(b*12+h)*512 + i0 + i)*8 + jt] = ssum;   // unique owner, plain store
  }
  #pragma unroll
  for (int u0=0; u0<6; u0++){
    int u = tid + u0*256;
    int h = u >> 7, rem = u & 127, i = rem >> 3, q = rem & 7;
    h8 v = *(const h8*)&S[(h*16 + i)*TS + q*8];
    *(h8*)(E + ((size_t)(b*12+h)*512 + i0 + i)*512 + j0 + q*8) = v;
  }
}

// ---------- K3b: PV MFMA from E via LDS-staged contiguous reads; colsum via LDS ----------
__global__ __launch_bounds__(256) void k_pv2(const f16* __restrict__ E,
    const f16* __restrict__ Vt, const float* __restrict__ lsump,
    float* __restrict__ O, float* __restrict__ colsum){
  __shared__ float csL[512];
  __shared__ __align__(16) f16 EL[4*16*256];   // 32 KB: wave w's 16 half-rows (512B each)
  int tid = threadIdx.x;
  int w = tid >> 6, lane = tid & 63;
  int kq = lane >> 4, mrow = lane & 15;
  int b = blockIdx.y;
  int bx = (blockIdx.x & 7)*12 + (blockIdx.x >> 3);     // XCD-chunked (96%8==0, bijective)
  int h = bx >> 3, it = bx & 7;
  int i0w = it*64 + w*16;

  csL[tid] = 0.f; csL[tid + 256] = 0.f;
  const float4* lp = (const float4*)(lsump + ((size_t)(b*12+h)*512 + i0w + mrow)*8);
  float4 p0 = lp[0], p1 = lp[1];
  float rinv = 1.f / (p0.x+p0.y+p0.z+p0.w + p1.x+p1.y+p1.z+p1.w);
  __syncthreads();

  const f16* ebase = E + ((size_t)(b*12+h)*512 + i0w)*512;   // wave's 16 rows
  const f16* vbase = Vt + ((size_t)(b*12+h)*64 + mrow)*512 + kq*8;
  char* Ew = (char*)EL + w*8192;                              // 16 rows x 512B

  f32x4 acc[4];
  #pragma unroll
  for (int nt=0; nt<4; nt++) acc[nt] = (f32x4){0.f,0.f,0.f,0.f};

  for (int ph=0; ph<2; ph++){
    // stage: 8 wave-loads, 2 rows per load (two 512B contiguous segments per instr)
    const f16* eb = ebase + ph*256;
    #pragma unroll
    for (int rr=0; rr<8; rr++){
      int r = rr*2 + (lane>>5);
      h8 v = *(const h8*)(eb + (size_t)r*512 + (lane&31)*8);
      *(h8*)(Ew + r*512 + (((lane&31)*16) ^ ((r&7)<<4))) = v;
    }
    #pragma unroll 4
    for (int jt2=0; jt2<8; jt2++){
      int jt = ph*8 + jt2;
      int j0 = jt*32;
      int co = jt2*64 + kq*16;                              // byte offset in 512B half-row
      h8 ea  = *(const h8*)(Ew + mrow*512 + (co ^ ((mrow&7)<<4)));
      h8 bf0 = *(const h8*)(vbase + j0);
      h8 bf1 = *(const h8*)(vbase + (size_t)16*512 + j0);
      h8 bf2 = *(const h8*)(vbase + (size_t)32*512 + j0);
      h8 bf3 = *(const h8*)(vbase + (size_t)48*512 + j0);
      acc[0] = __builtin_amdgcn_mfma_f32_16x16x32_f16(ea, bf0, acc[0], 0, 0, 0);
      acc[1] = __builtin_amdgcn_mfma_f32_16x16x32_f16(ea, bf1, acc[1], 0, 0, 0);
      acc[2] = __builtin_amdgcn_mfma_f32_16x16x32_f16(ea, bf2, acc[2], 0, 0, 0);
      acc[3] = __builtin_amdgcn_mfma_f32_16x16x32_f16(ea, bf3, acc[3], 0, 0, 0);
      float cs[8];
      #pragma unroll
      for (int t=0;t<8;t++) cs[t] = (float)ea[t] * rinv;
      #pragma unroll
      for (int t=0;t<8;t++){
        cs[t] += __shfl_xor(cs[t], 1); cs[t] += __shfl_xor(cs[t], 2);
        cs[t] += __shfl_xor(cs[t], 4); cs[t] += __shfl_xor(cs[t], 8);
      }
      if (mrow == 0){
        #pragma unroll
        for (int t=0;t<8;t++) atomicAdd(&csL[j0 + kq*8 + t], cs[t]);
      }
    }
  }
  __syncthreads();
  atomicAdd(&colsum[b*512 + tid],       csL[tid]       * (1.f/12.f));
  atomicAdd(&colsum[b*512 + 256 + tid], csL[tid + 256] * (1.f/12.f));

  #pragma unroll
  for (int r=0; r<4; r++){
    float g = __shfl(rinv, kq*4 + r);
    #pragma unroll
    for (int nt=0; nt<4; nt++)
      O[((size_t)(b*512) + i0w + kq*4 + r)*768 + h*64 + nt*16 + mrow] = acc[nt][r] * g;
  }
}

// ---------- K4: merged probs: softmax(O @ Wout^T + bout), branch by blockIdx.y ----------
// Vectorized: float4 / bf16x4 loads cut per-lane VMEM issue 252 -> 63 instructions.
__global__ __launch_bounds__(256) void k_probs_m(const float* OA, const float* OB,
    const void* WoA, const void* WoB, const void* boA, const void* boB,
    float* prA, float* prB, const int* __restrict__ flag, int sbase){
  int z = sbase + blockIdx.y;
  const float* O = z ? OB : OA;
  const void* Wout = z ? WoB : WoA;
  const void* bout = z ? boB : boA;
  float* probs = z ? prB : prA;
  int isb = *flag;
  int tid = threadIdx.x, wv = tid>>6, lane = tid&63;
  int m = blockIdx.x*4 + wv;
  const float* orow = O + (size_t)m*768;
  float acc[20];
  #pragma unroll
  for (int c=0;c<20;c++) acc[c]=0.f;
  #pragma unroll
  for (int i=0;i<3;i++){
    int d = i*256 + lane*4;
    float4 o = *(const float4*)(orow + d);
    #pragma unroll
    for (int c=0;c<20;c++){
      float4 w4 = ldf4(Wout, c*768 + d, isb);
      acc[c] += o.x*w4.x + o.y*w4.y + o.z*w4.z + o.w*w4.w;
    }
  }
  #pragma unroll
  for (int c=0;c<20;c++){
    #pragma unroll
    for (int off=1; off<64; off<<=1) acc[c] += __shfl_xor(acc[c], off, 64);
  }
  float mx = -3.4e38f;
  #pragma unroll
  for (int c=0;c<20;c++){ acc[c] += ldf(bout, c, isb); mx = fmaxf(mx, acc[c]); }
  float s=0.f;
  #pragma unroll
  for (int c=0;c<20;c++){ acc[c] = __expf(acc[c]-mx); s += acc[c]; }
  float inv = 1.f/s;
  if (lane == 0){
    float* pr = probs + (size_t)m*20;
    #pragma unroll
    for (int c=0;c<20;c++) pr[c] = acc[c]*inv;
  }
}

// ---------- K5: merged final: both branches' get_weights + weighted sum + output ----------
__global__ __launch_bounds__(512) void k_final_m(const int* __restrict__ ids,
    const float* __restrict__ cs0, const float* __restrict__ cs1,
    const float* __restrict__ pr0, const float* __restrict__ pr1,
    const int* __restrict__ flag, void* __restrict__ outp){
  __shared__ float red[8];
  __shared__ float bcast;
  __shared__ float pacc[8][20];
  __shared__ float osum[20];
  int b = blockIdx.x, tid = threadIdx.x;
  int wv = tid>>6, lane = tid&63;
  int msk = (ids[b*512+tid] != 0);
  for (int br=0; br<2; br++){
    const float* colsum = br ? cs1 : cs0;
    const float* probs  = br ? pr1 : pr0;
    float w = msk ? colsum[b*512+tid] : 0.f;
    float mx = w;
    #pragma unroll
    for (int off=1; off<64; off<<=1) mx = fmaxf(mx, __shfl_xor(mx, off, 64));
    if (lane==0) red[wv] = mx;
    __syncthreads();
    if (tid==0){ float m2 = red[0]; for (int k2=1;k2<8;k2++) m2 = fmaxf(m2, red[k2]); bcast = m2; }
    __syncthreads();
    float M = bcast;
    float e = __expf(w - M);
    float s = e;
    #pragma unroll
    for (int off=1; off<64; off<<=1) s += __shfl_xor(s, off, 64);
    if (lane==0) red[wv] = s;
    __syncthreads();
    if (tid==0){ float s2=0.f; for (int k2=0;k2<8;k2++) s2 += red[k2]; bcast = s2; }
    __syncthreads();
    float wn = e / bcast;
    float p[20];
    const float* pr = probs + ((size_t)b*512 + tid)*20;
    #pragma unroll
    for (int c=0;c<20;c++) p[c] = wn * pr[c];
    #pragma unroll
    for (int c=0;c<20;c++){
      #pragma unroll
      for (int off=1; off<64; off<<=1) p[c] += __shfl_xor(p[c], off, 64);
    }
    if (lane==0){
      #pragma unroll
      for (int c=0;c<20;c++) pacc[wv][c] = p[c];
    }
    __syncthreads();
    if (tid < 20){
      float s2 = 0.f;
      #pragma unroll
      for (int k2=0;k2<8;k2++) s2 += pacc[k2][tid];
      if (br == 0) osum[tid] = s2;
      else         osum[tid] += s2;
    }
    __syncthreads();
  }
  if (tid < 20){
    float v = osum[tid] * 0.5f;
    if (*flag) ((ushort*)outp)[b*20 + tid] = f2b(v);
    else       ((float*)outp)[b*20 + tid] = v;
  }
}

extern "C" void kernel_launch(void* const* d_in, const int* in_sizes, int n_in,
                              void* d_out, int out_size, void* d_ws, size_t ws_size,
                              hipStream_t stream){
  (void)in_sizes; (void)n_in; (void)out_size;
  const int*  ids = (const int*)d_in[0];
  const void* wvp = d_in[1];
  const void* emb = d_in[2];
  const void* Wt[2]  = {d_in[3], d_in[9]};
  const void* bt[2]  = {d_in[4], d_in[10]};
  const void* gm[2]  = {d_in[5], d_in[11]};
  const void* bet[2] = {d_in[6], d_in[12]};
  const void* Wo[2]  = {d_in[7], d_in[13]};
  const void* bo[2]  = {d_in[8], d_in[14]};

  char* p = (char*)d_ws;
  #define ALLOC(ty, name, cnt) ty* name = (ty*)p; p += sizeof(ty)*(size_t)(cnt)

  // ---- try BIG layout (dual buffers, 9 dispatches) ----
  p = (char*)d_ws;
  ALLOC(float, O0, 6291456);
  ALLOC(float, O1, 6291456);
  ALLOC(f16, Qh0, 6291456); ALLOC(f16, Kh0, 6291456); ALLOC(f16, Vt0, 6291456);
  ALLOC(f16, Qh1, 6291456); ALLOC(f16, Kh1, 6291456); ALLOC(f16, Vt1, 6291456);
  ALLOC(f16, Ah0, 6291456); ALLOC(f16, Wh0, 1769472);
  ALLOC(f16, Ah1, 2621440); ALLOC(f16, Wh1, 737280);
  ALLOC(float, probs0, 163840); ALLOC(float, probs1, 163840);
  ALLOC(float, zb_big, 16384);   // colsum0, colsum1
  ALLOC(int, flag_big, 4);
  ALLOC(f16, E_big, 50331648);
  size_t needBig = (size_t)(p - (char*)d_ws);

  if (ws_size >= needBig){
    float* colsum0 = zb_big;
    float* colsum1 = zb_big + 8192;
    int* flagp = flag_big; f16* E = E_big;
    // rowsum partial buffers alias the A-repack buffer (dead after k_gemm_m)
    float* lsump0 = (float*)Ah0;
    float* lsump1 = lsump0 + 786432;

    k_init<<<65, 256, 0, stream>>>((const ushort*)wvp, flagp, zb_big);
    k_prep_all<<<3072+864+1280+360, 256, 0, stream>>>(ids, emb, wvp, Wt[0], Wt[1],
        flagp, Ah0, Wh0, Ah1, Wh1, 3072, 864, 1280, 360);
    dim3 gg(64, 18, 2);
    k_gemm_m<<<gg, 256, 0, stream>>>(Ah0, Wh0, bt[0], 768, Qh0, Kh0, Vt0,
                                     Ah1, Wh1, bt[1], 320, Qh1, Kh1, Vt1, flagp, 0);
    dim3 gpv(96, 16);
    k_scores<<<4096, 256, 0, stream>>>(Qh0, Kh0, gm[0], bet[0], flagp, E, lsump0);
    k_pv2<<<gpv, 256, 0, stream>>>(E, Vt0, lsump0, O0, colsum0);
    k_scores<<<4096, 256, 0, stream>>>(Qh1, Kh1, gm[1], bet[1], flagp, E, lsump1);
    k_pv2<<<gpv, 256, 0, stream>>>(E, Vt1, lsump1, O1, colsum1);
    dim3 gpr(2048, 2);
    k_probs_m<<<gpr, 256, 0, stream>>>(O0, O1, Wo[0], Wo[1], bo[0], bo[1],
                                       probs0, probs1, flagp, 0);
    k_final_m<<<16, 512, 0, stream>>>(ids, colsum0, colsum1, probs0, probs1, flagp, d_out);
    return;
  }

  // ---- MID layout (shared big buffers, 12 dispatches) ----
  p = (char*)d_ws;
  ALLOC(float, O, 6291456);
  ALLOC(f16, Qh, 6291456); ALLOC(f16, Kh, 6291456); ALLOC(f16, Vt, 6291456);
  ALLOC(f16, Ah, 6291456); ALLOC(f16, Wh, 1769472);
  ALLOC(float, probsA, 163840); ALLOC(float, probsB, 163840);
  ALLOC(float, zb, 16384);
  ALLOC(int, flagm, 4);
  ALLOC(f16, Em, 50331648);
  float* colsum0 = zb;
  float* colsum1 = zb + 8192;
  // rowsum partials alias Ah (dead after each branch's k_gemm_m)
  float* lsumm0 = (float*)Ah;
  float* lsumm1 = lsumm0 + 786432;

  k_init<<<65, 256, 0, stream>>>((const ushort*)wvp, flagm, zb);
  // branch 0
  k_prep_all<<<3072+864, 256, 0, stream>>>(ids, emb, wvp, Wt[0], Wt[1],
      flagm, Ah, Wh, Ah, Wh, 3072, 864, 0, 0);
  dim3 g1(64, 18, 1);
  k_gemm_m<<<g1, 256, 0, stream>>>(Ah, Wh, bt[0], 768, Qh, Kh, Vt,
                                   Ah, Wh, bt[0], 768, Qh, Kh, Vt, flagm, 0);
  dim3 gpv(96, 16);
  k_scores<<<4096, 256, 0, stream>>>(Qh, Kh, gm[0], bet[0], flagm, Em, lsumm0);
  k_pv2<<<gpv, 256, 0, stream>>>(Em, Vt, lsumm0, O, colsum0);
  dim3 gpr(2048, 1);
  k_probs_m<<<gpr, 256, 0, stream>>>(O, O, Wo[0], Wo[1], bo[0], bo[1],
                                     probsA, probsB, flagm, 0);
  // branch 1 (reuse Ah/Wh/QKV/O)
  k_prep_all<<<1280+360, 256, 0, stream>>>(ids, emb, wvp, Wt[0], Wt[1],
      flagm, Ah, Wh, Ah, Wh, 0, 0, 1280, 360);
  k_gemm_m<<<g1, 256, 0, stream>>>(Ah, Wh, bt[1], 320, Qh, Kh, Vt,
                                   Ah, Wh, bt[1], 320, Qh, Kh, Vt, flagm, 0);
  k_scores<<<4096, 256, 0, stream>>>(Qh, Kh, gm[1], bet[1], flagm, Em, lsumm1);
  k_pv2<<<gpv, 256, 0, stream>>>(Em, Vt, lsumm1, O, colsum1);
  k_probs_m<<<gpr, 256, 0, stream>>>(O, O, Wo[0], Wo[1], bo[0], bo[1],
                                     probsA, probsB, flagm, 1);
  k_final_m<<<16, 512, 0, stream>>>(ids, colsum0, colsum1, probsA, probsB, flagm, d_out);
  #undef ALLOC
}

// Round 15
// 556.510 us; speedup vs baseline: 1.0750x; 1.0750x over previous
//
#include <hip/hip_runtime.h>

typedef unsigned int uint;
typedef unsigned short ushort;
typedef _Float16 f16;
typedef _Float16 h8 __attribute__((ext_vector_type(8)));
typedef float f32x4 __attribute__((ext_vector_type(4)));

// B=16 L=512 H=12 d=64 D=768 N3=2304 C=20 M=8192

__device__ __forceinline__ float b2f(ushort u){ return __uint_as_float(((uint)u)<<16); }
__device__ __forceinline__ ushort f2b(float f){
  uint u = __float_as_uint(f);
  uint r = u + 0x7fffu + ((u>>16)&1u);
  return (ushort)(r>>16);
}
__device__ __forceinline__ float leaky(float x){ return x >= 0.f ? x : 0.01f*x; }
__device__ __forceinline__ float ldf(const void* p, int idx, int isb){
  return isb ? b2f(((const ushort*)p)[idx]) : ((const float*)p)[idx];
}

#define GLOAD16(gp, lp) __builtin_amdgcn_global_load_lds( \
    (const __attribute__((address_space(1))) void*)(gp), \
    (__attribute__((address_space(3))) void*)(lp), 16, 0, 0)

// ---------- K_init: detect dtype (block 0) + zero colsum0/1 (blocks 1..64) ----------
__global__ __launch_bounds__(256) void k_init(const ushort* __restrict__ wvbits,
    int* __restrict__ flag, float* __restrict__ zbase){
  int bid = blockIdx.x, tid = threadIdx.x;
  if (bid == 0){
    if (tid == 0){
      int sane = 0;
      for (int i=0;i<128;i++){
        uint e = (wvbits[i]>>7)&0xffu;
        if (e==0u || (e>=90u && e<=150u)) sane++;
      }
      *flag = (sane >= 115) ? 1 : 0;
    }
  } else {
    zbase[(bid-1)*256 + tid] = 0.f;   // 64*256 = 16384 floats (colsum0+colsum1)
  }
}

// ---------- K_prep_all: build_x + up to 3 repacks, range-dispatched on blockIdx.x ----------
__global__ __launch_bounds__(256) void k_prep_all(const int* __restrict__ ids,
    const void* __restrict__ emb, const void* __restrict__ wv,
    const void* __restrict__ W0, const void* __restrict__ W1,
    const int* __restrict__ flag,
    f16* __restrict__ AhA, f16* __restrict__ WhA,
    f16* __restrict__ AhB, f16* __restrict__ WhB,
    int nBX, int nW0, int nA1, int nW1){
  int isb = *flag;
  int bx = blockIdx.x, tid = threadIdx.x;
  if (bx < nBX){
    int t = bx*256 + tid;            // 8192*96 units
    int m = t / 96, kk = (t % 96) * 8;
    float o[8];
    if (isb){
      const ushort* src = (const ushort*)emb + (size_t)ids[m]*768 + kk;
      uint4 v = *(const uint4*)src;
      o[0]=__uint_as_float((v.x&0xffffu)<<16); o[1]=__uint_as_float(v.x&0xffff0000u);
      o[2]=__uint_as_float((v.y&0xffffu)<<16); o[3]=__uint_as_float(v.y&0xffff0000u);
      o[4]=__uint_as_float((v.z&0xffffu)<<16); o[5]=__uint_as_float(v.z&0xffff0000u);
      o[6]=__uint_as_float((v.w&0xffffu)<<16); o[7]=__uint_as_float(v.w&0xffff0000u);
    } else {
      const float* src = (const float*)emb + (size_t)ids[m]*768 + kk;
      float4 v0 = ((const float4*)src)[0];
      float4 v1 = ((const float4*)src)[1];
      o[0]=v0.x; o[1]=v0.y; o[2]=v0.z; o[3]=v0.w;
      o[4]=v1.x; o[5]=v1.y; o[6]=v1.z; o[7]=v1.w;
    }
    h8 hv;
    #pragma unroll
    for (int i=0;i<8;i++) hv[i] = (f16)leaky(o[i]);
    *(h8*)(AhA + (size_t)m*768 + kk) = hv;
  } else if (bx < nBX + nW0){
    int t = (bx - nBX)*256 + tid;    // 2304*96 units
    int n = t / 96, kk = (t % 96) * 8;
    h8 hv;
    #pragma unroll
    for (int i=0;i<8;i++) hv[i] = (f16)ldf(W0, n*768 + kk + i, isb);
    *(h8*)(WhA + (size_t)n*768 + kk) = hv;
  } else if (bx < nBX + nW0 + nA1){
    int t = (bx - nBX - nW0)*256 + tid;  // 8192*40 units
    int n = t / 40, kk = (t % 40) * 8;
    h8 hv;
    #pragma unroll
    for (int i=0;i<8;i++){
      int k = kk + i;
      hv[i] = (k < 300) ? (f16)ldf(wv, n*300 + k, isb) : (f16)0.f;
    }
    *(h8*)(AhB + (size_t)n*320 + kk) = hv;
  } else {
    int t = (bx - nBX - nW0 - nA1)*256 + tid;  // 2304*40 units
    int n = t / 40, kk = (t % 40) * 8;
    h8 hv;
    #pragma unroll
    for (int i=0;i<8;i++){
      int k = kk + i;
      hv[i] = (k < 300) ? (f16)ldf(W1, n*300 + k, isb) : (f16)0.f;
    }
    *(h8*)(WhB + (size_t)n*320 + kk) = hv;
  }
}

// ---------- K1: merged MFMA QKV GEMM (branch by blockIdx.z), m97 LDS staging, fused QK-norm ----------
// Epilogue: wave-private LDS transpose (reuses staging buffer after sync) -> 8 coalesced h8
// stores per thread (1KB dense per wave-instr) instead of 64 scalar scattered f16 stores.
__global__ __launch_bounds__(256) void k_gemm_m(
    const f16* AhA, const f16* WhA, const void* biasA, int KA,
    f16* QhA, f16* KhA, f16* VtA,
    const f16* AhB, const f16* WhB, const void* biasB, int KB,
    f16* QhB, f16* KhB, f16* VtB,
    const int* __restrict__ flag, int sbase){
  __shared__ __align__(16) f16 SB[2*128*64];
  f16* As = SB;
  f16* Bs = SB + 128*64;
  int z = sbase + blockIdx.z;
  const f16* Ah = z ? AhB : AhA;
  const f16* Wh = z ? WhB : WhA;
  const void* bias = z ? biasB : biasA;
  int KP = z ? KB : KA;
  f16* Qh = z ? QhB : QhA;
  f16* Kh = z ? KhB : KhA;
  f16* Vt = z ? VtB : VtA;
  int STEPS = KP >> 6;

  int tid = threadIdx.x;
  int w = tid >> 6, lane = tid & 63;
  int mrow = lane & 15, kq = lane >> 4;
  int m0 = (((blockIdx.x & 7)<<3) | (blockIdx.x >> 3)) * 128;   // XCD-chunked (64%8==0)
  int n0 = blockIdx.y * 128;
  int msub = (w & 1) * 64, nsub = (w >> 1) * 64;

  f32x4 acc[4][4];
  #pragma unroll
  for (int mt=0; mt<4; mt++)
    #pragma unroll
    for (int nt=0; nt<4; nt++) acc[mt][nt] = (f32x4){0.f,0.f,0.f,0.f};

  int cbase = w*64 + lane;

  for (int step=0; step<STEPS; step++){
    int k0 = step*64;
    __syncthreads();
    #pragma unroll
    for (int rep=0; rep<4; rep++){
      int cb = rep*256 + w*64;
      int c  = rep*256 + cbase;
      int row = c >> 3;
      int qs  = (c & 7) ^ (row & 7);
      GLOAD16(Ah + (size_t)(m0+row)*KP + k0 + qs*8, As + cb*8);
      GLOAD16(Wh + (size_t)(n0+row)*KP + k0 + qs*8, Bs + cb*8);
    }
    __syncthreads();
    #pragma unroll
    for (int ks=0; ks<2; ks++){
      h8 af[4], bf[4];
      #pragma unroll
      for (int mt=0; mt<4; mt++){
        int row = msub + mt*16 + mrow;
        int slot = (ks*4 + kq) ^ (row & 7);
        af[mt] = *(const h8*)(As + row*64 + slot*8);
      }
      #pragma unroll
      for (int nt=0; nt<4; nt++){
        int row = nsub + nt*16 + mrow;
        int slot = (ks*4 + kq) ^ (row & 7);
        bf[nt] = *(const h8*)(Bs + row*64 + slot*8);
      }
      #pragma unroll
      for (int mt=0; mt<4; mt++)
        #pragma unroll
        for (int nt=0; nt<4; nt++)
          acc[mt][nt] = __builtin_amdgcn_mfma_f32_16x16x32_f16(af[mt], bf[nt], acc[mt][nt], 0, 0, 0);
    }
  }

  int isb = *flag;
  int n0w = n0 + nsub;
  int s = n0w / 768;
  int h = (n0w % 768) >> 6;
  float bv[4];
  #pragma unroll
  for (int nt=0; nt<4; nt++) bv[nt] = ldf(bias, n0w + nt*16 + mrow, isb);

  __syncthreads();                      // all MFMA reads of As/Bs done; reuse as transpose tile
  f16* tw = SB + w*4096;                // wave-private 64x64 f16 tile (8KB)

  #pragma unroll
  for (int mt=0; mt<4; mt++){
    float yv[4][4];
    #pragma unroll
    for (int nt=0; nt<4; nt++)
      #pragma unroll
      for (int r=0; r<4; r++)
        yv[nt][r] = leaky(acc[mt][nt][r] + bv[nt]);
    if (s < 2){
      #pragma unroll
      for (int r=0; r<4; r++){
        float ss = yv[0][r]*yv[0][r] + yv[1][r]*yv[1][r]
                 + yv[2][r]*yv[2][r] + yv[3][r]*yv[3][r];
        ss += __shfl_xor(ss, 1); ss += __shfl_xor(ss, 2);
        ss += __shfl_xor(ss, 4); ss += __shfl_xor(ss, 8);
        float rn = 1.f / fmaxf(sqrtf(ss), 1e-8f);
        #pragma unroll
        for (int nt=0; nt<4; nt++) yv[nt][r] *= rn;
      }
    }
    #pragma unroll
    for (int nt=0; nt<4; nt++){
      #pragma unroll
      for (int r=0; r<4; r++){
        int ml = mt*16 + kq*4 + r;      // local row in quadrant
        int dd = nt*16 + mrow;          // local col (d-index)
        if (s == 2) tw[dd*64 + (ml ^ ((dd&7)<<3))] = (f16)yv[nt][r];
        else        tw[ml*64 + (dd ^ ((ml&7)<<3))] = (f16)yv[nt][r];
      }
    }
  }
  // wave-private tile: in-wave lgkmcnt ordering suffices, no barrier

  int mq = m0 + msub;                   // quadrant base row (64-aligned, within one 512-block)
  int bq = mq >> 9, l0 = mq & 511;
  if (s < 2){
    f16* gb = (s == 0 ? Qh : Kh) + ((size_t)(bq*12 + h)*512 + l0)*64;
    #pragma unroll
    for (int ps=0; ps<8; ps++){
      int ml = ps*8 + (lane>>3);
      int d0 = (lane&7)*8;
      h8 v = *(const h8*)(tw + ml*64 + (d0 ^ ((ml&7)<<3)));
      *(h8*)(gb + (size_t)ml*64 + d0) = v;    // 8 rows x 128B dense per wave-instr
    }
  } else {
    f16* gb = Vt + ((size_t)(bq*12 + h)*64)*512 + l0;
    #pragma unroll
    for (int ps=0; ps<8; ps++){
      int dd = ps*8 + (lane>>3);
      int m8 = (lane&7)*8;
      h8 v = *(const h8*)(tw + dd*64 + (m8 ^ ((dd&7)<<3)));
      *(h8*)(gb + (size_t)dd*512 + m8) = v;   // 8 dd-rows x 128B dense per wave-instr
    }
  }
}

// ---------- K3a: scores -> head-LN -> exp -> E (fp16) + rowsum PARTIALS (r9 proven body) ----------
__global__ __launch_bounds__(256) void k_scores(const f16* __restrict__ Qh,
    const f16* __restrict__ Kh, const void* __restrict__ gamma,
    const void* __restrict__ beta, const int* __restrict__ flag,
    f16* __restrict__ E, float* __restrict__ lsump){
  constexpr int TS = 72;
  __shared__ f16 S[12*16*TS];
  __shared__ float gL[12], beL[12];

  int tid = threadIdx.x;
  int w = tid >> 6, lane = tid & 63;
  int kq = lane >> 4, mrow = lane & 15;
  int bx = (blockIdx.x & 7)*512 + (blockIdx.x >> 3);   // XCD-chunked (4096%8==0, bijective)
  int jt = bx & 7, it = (bx >> 3) & 31, b = bx >> 8;
  int i0 = it*16, j0 = jt*64;

  if (tid < 12){ int isb = *flag; gL[tid] = ldf(gamma, tid, isb); beL[tid] = ldf(beta, tid, isb); }

  #pragma unroll
  for (int hh=0; hh<3; hh++){
    int h = w*3 + hh;
    const f16* kb = Kh + ((size_t)(b*12+h)*512 + i0 + mrow)*64;
    h8 a0 = *(const h8*)(kb + kq*8);
    h8 a1 = *(const h8*)(kb + 32 + kq*8);
    const f16* qb = Qh + ((size_t)(b*12+h)*512 + j0)*64;
    #pragma unroll
    for (int jn=0; jn<4; jn++){
      const f16* qr = qb + (size_t)(jn*16 + mrow)*64;
      h8 q0 = *(const h8*)(qr + kq*8);
      h8 q1 = *(const h8*)(qr + 32 + kq*8);
      f32x4 c = (f32x4){0.f,0.f,0.f,0.f};
      c = __builtin_amdgcn_mfma_f32_16x16x32_f16(a0, q0, c, 0, 0, 0);
      c = __builtin_amdgcn_mfma_f32_16x16x32_f16(a1, q1, c, 0, 0, 0);
      #pragma unroll
      for (int r=0;r<4;r++)
        S[(h*16 + kq*4 + r)*TS + jn*16 + mrow] = (f16)c[r];
    }
  }
  __syncthreads();
  int pj = tid & 63, piw = tid >> 6;
  #pragma unroll
  for (int p=0; p<4; p++){
    int i = piw*4 + p;
    float s[12];
    float mu = 0.f, sq = 0.f;
    #pragma unroll
    for (int h=0;h<12;h++){ s[h] = (float)S[(h*16+i)*TS + pj]; mu += s[h]; sq += s[h]*s[h]; }
    mu *= (1.f/12.f);
    float var = fmaxf(sq*(1.f/12.f) - mu*mu, 0.f);
    float rstd = rsqrtf(var + 1e-5f);
    #pragma unroll
    for (int h=0;h<12;h++){
      float e = __expf((s[h]-mu)*rstd*gL[h] + beL[h]);
      S[(h*16+i)*TS + pj] = (f16)e;
    }
  }
  __syncthreads();
  if (tid < 192){
    int h = tid >> 4, i = tid & 15;
    const f16* zr = &S[(h*16 + i)*TS];
    float ssum = 0.f;
    #pragma unroll
    for (int q=0;q<8;q++){
      h8 v = *(const h8*)(zr + q*8);
      #pragma unroll
      for (int t=0;t<8;t++) ssum += (float)v[t];
    }
    lsump[((size_t)(b*12+h)*512 + i0 + i)*8 + jt] = ssum;   // unique owner, plain store
  }
  #pragma unroll
  for (int u0=0; u0<6; u0++){
    int u = tid + u0*256;
    int h = u >> 7, rem = u & 127, i = rem >> 3, q = rem & 7;
    h8 v = *(const h8*)&S[(h*16 + i)*TS + q*8];
    *(h8*)(E + ((size_t)(b*12+h)*512 + i0 + i)*512 + j0 + q*8) = v;
  }
}

// ---------- K3b: PV MFMA from E via LDS-staged contiguous reads; colsum via LDS ----------
__global__ __launch_bounds__(256) void k_pv2(const f16* __restrict__ E,
    const f16* __restrict__ Vt, const float* __restrict__ lsump,
    float* __restrict__ O, float* __restrict__ colsum){
  __shared__ float csL[512];
  __shared__ __align__(16) f16 EL[4*16*256];   // 32 KB: wave w's 16 half-rows (512B each)
  int tid = threadIdx.x;
  int w = tid >> 6, lane = tid & 63;
  int kq = lane >> 4, mrow = lane & 15;
  int b = blockIdx.y;
  int bx = (blockIdx.x & 7)*12 + (blockIdx.x >> 3);     // XCD-chunked (96%8==0, bijective)
  int h = bx >> 3, it = bx & 7;
  int i0w = it*64 + w*16;

  csL[tid] = 0.f; csL[tid + 256] = 0.f;
  const float4* lp = (const float4*)(lsump + ((size_t)(b*12+h)*512 + i0w + mrow)*8);
  float4 p0 = lp[0], p1 = lp[1];
  float rinv = 1.f / (p0.x+p0.y+p0.z+p0.w + p1.x+p1.y+p1.z+p1.w);
  __syncthreads();

  const f16* ebase = E + ((size_t)(b*12+h)*512 + i0w)*512;   // wave's 16 rows
  const f16* vbase = Vt + ((size_t)(b*12+h)*64 + mrow)*512 + kq*8;
  char* Ew = (char*)EL + w*8192;                              // 16 rows x 512B

  f32x4 acc[4];
  #pragma unroll
  for (int nt=0; nt<4; nt++) acc[nt] = (f32x4){0.f,0.f,0.f,0.f};

  for (int ph=0; ph<2; ph++){
    // stage: 8 wave-loads, 2 rows per load (two 512B contiguous segments per instr)
    const f16* eb = ebase + ph*256;
    #pragma unroll
    for (int rr=0; rr<8; rr++){
      int r = rr*2 + (lane>>5);
      h8 v = *(const h8*)(eb + (size_t)r*512 + (lane&31)*8);
      *(h8*)(Ew + r*512 + (((lane&31)*16) ^ ((r&7)<<4))) = v;
    }
    #pragma unroll 4
    for (int jt2=0; jt2<8; jt2++){
      int jt = ph*8 + jt2;
      int j0 = jt*32;
      int co = jt2*64 + kq*16;                              // byte offset in 512B half-row
      h8 ea  = *(const h8*)(Ew + mrow*512 + (co ^ ((mrow&7)<<4)));
      h8 bf0 = *(const h8*)(vbase + j0);
      h8 bf1 = *(const h8*)(vbase + (size_t)16*512 + j0);
      h8 bf2 = *(const h8*)(vbase + (size_t)32*512 + j0);
      h8 bf3 = *(const h8*)(vbase + (size_t)48*512 + j0);
      acc[0] = __builtin_amdgcn_mfma_f32_16x16x32_f16(ea, bf0, acc[0], 0, 0, 0);
      acc[1] = __builtin_amdgcn_mfma_f32_16x16x32_f16(ea, bf1, acc[1], 0, 0, 0);
      acc[2] = __builtin_amdgcn_mfma_f32_16x16x32_f16(ea, bf2, acc[2], 0, 0, 0);
      acc[3] = __builtin_amdgcn_mfma_f32_16x16x32_f16(ea, bf3, acc[3], 0, 0, 0);
      float cs[8];
      #pragma unroll
      for (int t=0;t<8;t++) cs[t] = (float)ea[t] * rinv;
      #pragma unroll
      for (int t=0;t<8;t++){
        cs[t] += __shfl_xor(cs[t], 1); cs[t] += __shfl_xor(cs[t], 2);
        cs[t] += __shfl_xor(cs[t], 4); cs[t] += __shfl_xor(cs[t], 8);
      }
      if (mrow == 0){
        #pragma unroll
        for (int t=0;t<8;t++) atomicAdd(&csL[j0 + kq*8 + t], cs[t]);
      }
    }
  }
  __syncthreads();
  atomicAdd(&colsum[b*512 + tid],       csL[tid]       * (1.f/12.f));
  atomicAdd(&colsum[b*512 + 256 + tid], csL[tid + 256] * (1.f/12.f));

  #pragma unroll
  for (int r=0; r<4; r++){
    float g = __shfl(rinv, kq*4 + r);
    #pragma unroll
    for (int nt=0; nt<4; nt++)
      O[((size_t)(b*512) + i0w + kq*4 + r)*768 + h*64 + nt*16 + mrow] = acc[nt][r] * g;
  }
}

// ---------- K4: merged probs: softmax(O @ Wout^T + bout), branch by blockIdx.y ----------
__global__ __launch_bounds__(256) void k_probs_m(const float* OA, const float* OB,
    const void* WoA, const void* WoB, const void* boA, const void* boB,
    float* prA, float* prB, const int* __restrict__ flag, int sbase){
  int z = sbase + blockIdx.y;
  const float* O = z ? OB : OA;
  const void* Wout = z ? WoB : WoA;
  const void* bout = z ? boB : boA;
  float* probs = z ? prB : prA;
  int isb = *flag;
  int tid = threadIdx.x, wv = tid>>6, lane = tid&63;
  int m = blockIdx.x*4 + wv;
  const float* orow = O + (size_t)m*768;
  float acc[20];
  #pragma unroll
  for (int c=0;c<20;c++) acc[c]=0.f;
  for (int kk=0; kk<12; kk++){
    float o = orow[kk*64 + lane];
    #pragma unroll
    for (int c=0;c<20;c++)
      acc[c] += o * ldf(Wout, c*768 + kk*64 + lane, isb);
  }
  #pragma unroll
  for (int c=0;c<20;c++){
    #pragma unroll
    for (int off=1; off<64; off<<=1) acc[c] += __shfl_xor(acc[c], off, 64);
  }
  float mx = -3.4e38f;
  #pragma unroll
  for (int c=0;c<20;c++){ acc[c] += ldf(bout, c, isb); mx = fmaxf(mx, acc[c]); }
  float s=0.f;
  #pragma unroll
  for (int c=0;c<20;c++){ acc[c] = __expf(acc[c]-mx); s += acc[c]; }
  float inv = 1.f/s;
  if (lane == 0){
    float* pr = probs + (size_t)m*20;
    #pragma unroll
    for (int c=0;c<20;c++) pr[c] = acc[c]*inv;
  }
}

// ---------- K5: merged final: both branches' get_weights + weighted sum + output ----------
__global__ __launch_bounds__(512) void k_final_m(const int* __restrict__ ids,
    const float* __restrict__ cs0, const float* __restrict__ cs1,
    const float* __restrict__ pr0, const float* __restrict__ pr1,
    const int* __restrict__ flag, void* __restrict__ outp){
  __shared__ float red[8];
  __shared__ float bcast;
  __shared__ float pacc[8][20];
  __shared__ float osum[20];
  int b = blockIdx.x, tid = threadIdx.x;
  int wv = tid>>6, lane = tid&63;
  int msk = (ids[b*512+tid] != 0);
  for (int br=0; br<2; br++){
    const float* colsum = br ? cs1 : cs0;
    const float* probs  = br ? pr1 : pr0;
    float w = msk ? colsum[b*512+tid] : 0.f;
    float mx = w;
    #pragma unroll
    for (int off=1; off<64; off<<=1) mx = fmaxf(mx, __shfl_xor(mx, off, 64));
    if (lane==0) red[wv] = mx;
    __syncthreads();
    if (tid==0){ float m2 = red[0]; for (int k2=1;k2<8;k2++) m2 = fmaxf(m2, red[k2]); bcast = m2; }
    __syncthreads();
    float M = bcast;
    float e = __expf(w - M);
    float s = e;
    #pragma unroll
    for (int off=1; off<64; off<<=1) s += __shfl_xor(s, off, 64);
    if (lane==0) red[wv] = s;
    __syncthreads();
    if (tid==0){ float s2=0.f; for (int k2=0;k2<8;k2++) s2 += red[k2]; bcast = s2; }
    __syncthreads();
    float wn = e / bcast;
    float p[20];
    const float* pr = probs + ((size_t)b*512 + tid)*20;
    #pragma unroll
    for (int c=0;c<20;c++) p[c] = wn * pr[c];
    #pragma unroll
    for (int c=0;c<20;c++){
      #pragma unroll
      for (int off=1; off<64; off<<=1) p[c] += __shfl_xor(p[c], off, 64);
    }
    if (lane==0){
      #pragma unroll
      for (int c=0;c<20;c++) pacc[wv][c] = p[c];
    }
    __syncthreads();
    if (tid < 20){
      float s2 = 0.f;
      #pragma unroll
      for (int k2=0;k2<8;k2++) s2 += pacc[k2][tid];
      if (br == 0) osum[tid] = s2;
      else         osum[tid] += s2;
    }
    __syncthreads();
  }
  if (tid < 20){
    float v = osum[tid] * 0.5f;
    if (*flag) ((ushort*)outp)[b*20 + tid] = f2b(v);
    else       ((float*)outp)[b*20 + tid] = v;
  }
}

extern "C" void kernel_launch(void* const* d_in, const int* in_sizes, int n_in,
                              void* d_out, int out_size, void* d_ws, size_t ws_size,
                              hipStream_t stream){
  (void)in_sizes; (void)n_in; (void)out_size;
  const int*  ids = (const int*)d_in[0];
  const void* wvp = d_in[1];
  const void* emb = d_in[2];
  const void* Wt[2]  = {d_in[3], d_in[9]};
  const void* bt[2]  = {d_in[4], d_in[10]};
  const void* gm[2]  = {d_in[5], d_in[11]};
  const void* bet[2] = {d_in[6], d_in[12]};
  const void* Wo[2]  = {d_in[7], d_in[13]};
  const void* bo[2]  = {d_in[8], d_in[14]};

  char* p = (char*)d_ws;
  #define ALLOC(ty, name, cnt) ty* name = (ty*)p; p += sizeof(ty)*(size_t)(cnt)

  // ---- try BIG layout (dual buffers, 9 dispatches) ----
  p = (char*)d_ws;
  ALLOC(float, O0, 6291456);
  ALLOC(float, O1, 6291456);
  ALLOC(f16, Qh0, 6291456); ALLOC(f16, Kh0, 6291456); ALLOC(f16, Vt0, 6291456);
  ALLOC(f16, Qh1, 6291456); ALLOC(f16, Kh1, 6291456); ALLOC(f16, Vt1, 6291456);
  ALLOC(f16, Ah0, 6291456); ALLOC(f16, Wh0, 1769472);
  ALLOC(f16, Ah1, 2621440); ALLOC(f16, Wh1, 737280);
  ALLOC(float, probs0, 163840); ALLOC(float, probs1, 163840);
  ALLOC(float, zb_big, 16384);   // colsum0, colsum1
  ALLOC(int, flag_big, 4);
  ALLOC(f16, E_big, 50331648);
  size_t needBig = (size_t)(p - (char*)d_ws);

  if (ws_size >= needBig){
    float* colsum0 = zb_big;
    float* colsum1 = zb_big + 8192;
    int* flagp = flag_big; f16* E = E_big;
    // rowsum partial buffers alias the A-repack buffer (dead after k_gemm_m)
    float* lsump0 = (float*)Ah0;
    float* lsump1 = lsump0 + 786432;

    k_init<<<65, 256, 0, stream>>>((const ushort*)wvp, flagp, zb_big);
    k_prep_all<<<3072+864+1280+360, 256, 0, stream>>>(ids, emb, wvp, Wt[0], Wt[1],
        flagp, Ah0, Wh0, Ah1, Wh1, 3072, 864, 1280, 360);
    dim3 gg(64, 18, 2);
    k_gemm_m<<<gg, 256, 0, stream>>>(Ah0, Wh0, bt[0], 768, Qh0, Kh0, Vt0,
                                     Ah1, Wh1, bt[1], 320, Qh1, Kh1, Vt1, flagp, 0);
    dim3 gpv(96, 16);
    k_scores<<<4096, 256, 0, stream>>>(Qh0, Kh0, gm[0], bet[0], flagp, E, lsump0);
    k_pv2<<<gpv, 256, 0, stream>>>(E, Vt0, lsump0, O0, colsum0);
    k_scores<<<4096, 256, 0, stream>>>(Qh1, Kh1, gm[1], bet[1], flagp, E, lsump1);
    k_pv2<<<gpv, 256, 0, stream>>>(E, Vt1, lsump1, O1, colsum1);
    dim3 gpr(2048, 2);
    k_probs_m<<<gpr, 256, 0, stream>>>(O0, O1, Wo[0], Wo[1], bo[0], bo[1],
                                       probs0, probs1, flagp, 0);
    k_final_m<<<16, 512, 0, stream>>>(ids, colsum0, colsum1, probs0, probs1, flagp, d_out);
    return;
  }

  // ---- MID layout (shared big buffers, 12 dispatches) ----
  p = (char*)d_ws;
  ALLOC(float, O, 6291456);
  ALLOC(f16, Qh, 6291456); ALLOC(f16, Kh, 6291456); ALLOC(f16, Vt, 6291456);
  ALLOC(f16, Ah, 6291456); ALLOC(f16, Wh, 1769472);
  ALLOC(float, probsA, 163840); ALLOC(float, probsB, 163840);
  ALLOC(float, zb, 16384);
  ALLOC(int, flagm, 4);
  ALLOC(f16, Em, 50331648);
  float* colsum0 = zb;
  float* colsum1 = zb + 8192;
  // rowsum partials alias Ah (dead after each branch's k_gemm_m)
  float* lsumm0 = (float*)Ah;
  float* lsumm1 = lsumm0 + 786432;

  k_init<<<65, 256, 0, stream>>>((const ushort*)wvp, flagm, zb);
  // branch 0
  k_prep_all<<<3072+864, 256, 0, stream>>>(ids, emb, wvp, Wt[0], Wt[1],
      flagm, Ah, Wh, Ah, Wh, 3072, 864, 0, 0);
  dim3 g1(64, 18, 1);
  k_gemm_m<<<g1, 256, 0, stream>>>(Ah, Wh, bt[0], 768, Qh, Kh, Vt,
                                   Ah, Wh, bt[0], 768, Qh, Kh, Vt, flagm, 0);
  dim3 gpv(96, 16);
  k_scores<<<4096, 256, 0, stream>>>(Qh, Kh, gm[0], bet[0], flagm, Em, lsumm0);
  k_pv2<<<gpv, 256, 0, stream>>>(Em, Vt, lsumm0, O, colsum0);
  dim3 gpr(2048, 1);
  k_probs_m<<<gpr, 256, 0, stream>>>(O, O, Wo[0], Wo[1], bo[0], bo[1],
                                     probsA, probsB, flagm, 0);
  // branch 1 (reuse Ah/Wh/QKV/O)
  k_prep_all<<<1280+360, 256, 0, stream>>>(ids, emb, wvp, Wt[0], Wt[1],
      flagm, Ah, Wh, Ah, Wh, 0, 0, 1280, 360);
  k_gemm_m<<<g1, 256, 0, stream>>>(Ah, Wh, bt[1], 320, Qh, Kh, Vt,
                                   Ah, Wh, bt[1], 320, Qh, Kh, Vt, flagm, 0);
  k_scores<<<4096, 256, 0, stream>>>(Qh, Kh, gm[1], bet[1], flagm, Em, lsumm1);
  k_pv2<<<gpv, 256, 0, stream>>>(Em, Vt, lsumm1, O, colsum1);
  k_probs_m<<<gpr, 256, 0, stream>>>(O, O, Wo[0], Wo[1], bo[0], bo[1],
                                     probsA, probsB, flagm, 1);
  k_final_m<<<16, 512, 0, stream>>>(ids, colsum0, colsum1, probsA, probsB, flagm, d_out);
  #undef ALLOC
}

// Round 16
// 554.567 us; speedup vs baseline: 1.0788x; 1.0035x over previous
//
#include <hip/hip_runtime.h>

typedef unsigned int uint;
typedef unsigned short ushort;
typedef _Float16 f16;
typedef _Float16 h8 __attribute__((ext_vector_type(8)));
typedef float f32x4 __attribute__((ext_vector_type(4)));

// B=16 L=512 H=12 d=64 D=768 N3=2304 C=20 M=8192

__device__ __forceinline__ float b2f(ushort u){ return __uint_as_float(((uint)u)<<16); }
__device__ __forceinline__ ushort f2b(float f){
  uint u = __float_as_uint(f);
  uint r = u + 0x7fffu + ((u>>16)&1u);
  return (ushort)(r>>16);
}
__device__ __forceinline__ float leaky(float x){ return x >= 0.f ? x : 0.01f*x; }
__device__ __forceinline__ float ldf(const void* p, int idx, int isb){
  return isb ? b2f(((const ushort*)p)[idx]) : ((const float*)p)[idx];
}

#define GLOAD16(gp, lp) __builtin_amdgcn_global_load_lds( \
    (const __attribute__((address_space(1))) void*)(gp), \
    (__attribute__((address_space(3))) void*)(lp), 16, 0, 0)

// ---------- K_init: detect dtype (block 0) + zero colsum0/1 (blocks 1..64) ----------
__global__ __launch_bounds__(256) void k_init(const ushort* __restrict__ wvbits,
    int* __restrict__ flag, float* __restrict__ zbase){
  int bid = blockIdx.x, tid = threadIdx.x;
  if (bid == 0){
    if (tid == 0){
      int sane = 0;
      for (int i=0;i<128;i++){
        uint e = (wvbits[i]>>7)&0xffu;
        if (e==0u || (e>=90u && e<=150u)) sane++;
      }
      *flag = (sane >= 115) ? 1 : 0;
    }
  } else {
    zbase[(bid-1)*256 + tid] = 0.f;   // 64*256 = 16384 floats (colsum0+colsum1)
  }
}

// ---------- K_prep_all: build_x + up to 3 repacks, range-dispatched on blockIdx.x ----------
__global__ __launch_bounds__(256) void k_prep_all(const int* __restrict__ ids,
    const void* __restrict__ emb, const void* __restrict__ wv,
    const void* __restrict__ W0, const void* __restrict__ W1,
    const int* __restrict__ flag,
    f16* __restrict__ AhA, f16* __restrict__ WhA,
    f16* __restrict__ AhB, f16* __restrict__ WhB,
    int nBX, int nW0, int nA1, int nW1){
  int isb = *flag;
  int bx = blockIdx.x, tid = threadIdx.x;
  if (bx < nBX){
    int t = bx*256 + tid;            // 8192*96 units
    int m = t / 96, kk = (t % 96) * 8;
    float o[8];
    if (isb){
      const ushort* src = (const ushort*)emb + (size_t)ids[m]*768 + kk;
      uint4 v = *(const uint4*)src;
      o[0]=__uint_as_float((v.x&0xffffu)<<16); o[1]=__uint_as_float(v.x&0xffff0000u);
      o[2]=__uint_as_float((v.y&0xffffu)<<16); o[3]=__uint_as_float(v.y&0xffff0000u);
      o[4]=__uint_as_float((v.z&0xffffu)<<16); o[5]=__uint_as_float(v.z&0xffff0000u);
      o[6]=__uint_as_float((v.w&0xffffu)<<16); o[7]=__uint_as_float(v.w&0xffff0000u);
    } else {
      const float* src = (const float*)emb + (size_t)ids[m]*768 + kk;
      float4 v0 = ((const float4*)src)[0];
      float4 v1 = ((const float4*)src)[1];
      o[0]=v0.x; o[1]=v0.y; o[2]=v0.z; o[3]=v0.w;
      o[4]=v1.x; o[5]=v1.y; o[6]=v1.z; o[7]=v1.w;
    }
    h8 hv;
    #pragma unroll
    for (int i=0;i<8;i++) hv[i] = (f16)leaky(o[i]);
    *(h8*)(AhA + (size_t)m*768 + kk) = hv;
  } else if (bx < nBX + nW0){
    int t = (bx - nBX)*256 + tid;    // 2304*96 units
    int n = t / 96, kk = (t % 96) * 8;
    h8 hv;
    #pragma unroll
    for (int i=0;i<8;i++) hv[i] = (f16)ldf(W0, n*768 + kk + i, isb);
    *(h8*)(WhA + (size_t)n*768 + kk) = hv;
  } else if (bx < nBX + nW0 + nA1){
    int t = (bx - nBX - nW0)*256 + tid;  // 8192*40 units
    int n = t / 40, kk = (t % 40) * 8;
    h8 hv;
    #pragma unroll
    for (int i=0;i<8;i++){
      int k = kk + i;
      hv[i] = (k < 300) ? (f16)ldf(wv, n*300 + k, isb) : (f16)0.f;
    }
    *(h8*)(AhB + (size_t)n*320 + kk) = hv;
  } else {
    int t = (bx - nBX - nW0 - nA1)*256 + tid;  // 2304*40 units
    int n = t / 40, kk = (t % 40) * 8;
    h8 hv;
    #pragma unroll
    for (int i=0;i<8;i++){
      int k = kk + i;
      hv[i] = (k < 300) ? (f16)ldf(W1, n*300 + k, isb) : (f16)0.f;
    }
    *(h8*)(WhB + (size_t)n*320 + kk) = hv;
  }
}

// ---------- K1: merged MFMA QKV GEMM (branch by blockIdx.z), m97 LDS staging, fused QK-norm ----------
// Epilogue: wave-private LDS transpose (reuses staging buffer after sync) -> 8 coalesced h8
// stores per thread (1KB dense per wave-instr) instead of 64 scalar scattered f16 stores.
__global__ __launch_bounds__(256) void k_gemm_m(
    const f16* AhA, const f16* WhA, const void* biasA, int KA,
    f16* QhA, f16* KhA, f16* VtA,
    const f16* AhB, const f16* WhB, const void* biasB, int KB,
    f16* QhB, f16* KhB, f16* VtB,
    const int* __restrict__ flag, int sbase){
  __shared__ __align__(16) f16 SB[2*128*64];
  f16* As = SB;
  f16* Bs = SB + 128*64;
  int z = sbase + blockIdx.z;
  const f16* Ah = z ? AhB : AhA;
  const f16* Wh = z ? WhB : WhA;
  const void* bias = z ? biasB : biasA;
  int KP = z ? KB : KA;
  f16* Qh = z ? QhB : QhA;
  f16* Kh = z ? KhB : KhA;
  f16* Vt = z ? VtB : VtA;
  int STEPS = KP >> 6;

  int tid = threadIdx.x;
  int w = tid >> 6, lane = tid & 63;
  int mrow = lane & 15, kq = lane >> 4;
  int m0 = (((blockIdx.x & 7)<<3) | (blockIdx.x >> 3)) * 128;   // XCD-chunked (64%8==0)
  int n0 = blockIdx.y * 128;
  int msub = (w & 1) * 64, nsub = (w >> 1) * 64;

  f32x4 acc[4][4];
  #pragma unroll
  for (int mt=0; mt<4; mt++)
    #pragma unroll
    for (int nt=0; nt<4; nt++) acc[mt][nt] = (f32x4){0.f,0.f,0.f,0.f};

  int cbase = w*64 + lane;

  for (int step=0; step<STEPS; step++){
    int k0 = step*64;
    __syncthreads();
    #pragma unroll
    for (int rep=0; rep<4; rep++){
      int cb = rep*256 + w*64;
      int c  = rep*256 + cbase;
      int row = c >> 3;
      int qs  = (c & 7) ^ (row & 7);
      GLOAD16(Ah + (size_t)(m0+row)*KP + k0 + qs*8, As + cb*8);
      GLOAD16(Wh + (size_t)(n0+row)*KP + k0 + qs*8, Bs + cb*8);
    }
    __syncthreads();
    #pragma unroll
    for (int ks=0; ks<2; ks++){
      h8 af[4], bf[4];
      #pragma unroll
      for (int mt=0; mt<4; mt++){
        int row = msub + mt*16 + mrow;
        int slot = (ks*4 + kq) ^ (row & 7);
        af[mt] = *(const h8*)(As + row*64 + slot*8);
      }
      #pragma unroll
      for (int nt=0; nt<4; nt++){
        int row = nsub + nt*16 + mrow;
        int slot = (ks*4 + kq) ^ (row & 7);
        bf[nt] = *(const h8*)(Bs + row*64 + slot*8);
      }
      #pragma unroll
      for (int mt=0; mt<4; mt++)
        #pragma unroll
        for (int nt=0; nt<4; nt++)
          acc[mt][nt] = __builtin_amdgcn_mfma_f32_16x16x32_f16(af[mt], bf[nt], acc[mt][nt], 0, 0, 0);
    }
  }

  int isb = *flag;
  int n0w = n0 + nsub;
  int s = n0w / 768;
  int h = (n0w % 768) >> 6;
  float bv[4];
  #pragma unroll
  for (int nt=0; nt<4; nt++) bv[nt] = ldf(bias, n0w + nt*16 + mrow, isb);

  __syncthreads();                      // all MFMA reads of As/Bs done; reuse as transpose tile
  f16* tw = SB + w*4096;                // wave-private 64x64 f16 tile (8KB)

  #pragma unroll
  for (int mt=0; mt<4; mt++){
    float yv[4][4];
    #pragma unroll
    for (int nt=0; nt<4; nt++)
      #pragma unroll
      for (int r=0; r<4; r++)
        yv[nt][r] = leaky(acc[mt][nt][r] + bv[nt]);
    if (s < 2){
      #pragma unroll
      for (int r=0; r<4; r++){
        float ss = yv[0][r]*yv[0][r] + yv[1][r]*yv[1][r]
                 + yv[2][r]*yv[2][r] + yv[3][r]*yv[3][r];
        ss += __shfl_xor(ss, 1); ss += __shfl_xor(ss, 2);
        ss += __shfl_xor(ss, 4); ss += __shfl_xor(ss, 8);
        float rn = 1.f / fmaxf(sqrtf(ss), 1e-8f);
        #pragma unroll
        for (int nt=0; nt<4; nt++) yv[nt][r] *= rn;
      }
    }
    #pragma unroll
    for (int nt=0; nt<4; nt++){
      #pragma unroll
      for (int r=0; r<4; r++){
        int ml = mt*16 + kq*4 + r;      // local row in quadrant
        int dd = nt*16 + mrow;          // local col (d-index)
        if (s == 2) tw[dd*64 + (ml ^ ((dd&7)<<3))] = (f16)yv[nt][r];
        else        tw[ml*64 + (dd ^ ((ml&7)<<3))] = (f16)yv[nt][r];
      }
    }
  }
  // wave-private tile: in-wave lgkmcnt ordering suffices, no barrier

  int mq = m0 + msub;                   // quadrant base row (64-aligned, within one 512-block)
  int bq = mq >> 9, l0 = mq & 511;
  if (s < 2){
    f16* gb = (s == 0 ? Qh : Kh) + ((size_t)(bq*12 + h)*512 + l0)*64;
    #pragma unroll
    for (int ps=0; ps<8; ps++){
      int ml = ps*8 + (lane>>3);
      int d0 = (lane&7)*8;
      h8 v = *(const h8*)(tw + ml*64 + (d0 ^ ((ml&7)<<3)));
      *(h8*)(gb + (size_t)ml*64 + d0) = v;    // 8 rows x 128B dense per wave-instr
    }
  } else {
    f16* gb = Vt + ((size_t)(bq*12 + h)*64)*512 + l0;
    #pragma unroll
    for (int ps=0; ps<8; ps++){
      int dd = ps*8 + (lane>>3);
      int m8 = (lane&7)*8;
      h8 v = *(const h8*)(tw + dd*64 + (m8 ^ ((dd&7)<<3)));
      *(h8*)(gb + (size_t)dd*512 + m8) = v;   // 8 dd-rows x 128B dense per wave-instr
    }
  }
}

// ---------- K3a: scores -> head-LN -> exp -> E (fp16) + rowsum PARTIALS (r9 proven body) ----------
__global__ __launch_bounds__(256) void k_scores(const f16* __restrict__ Qh,
    const f16* __restrict__ Kh, const void* __restrict__ gamma,
    const void* __restrict__ beta, const int* __restrict__ flag,
    f16* __restrict__ E, float* __restrict__ lsump){
  constexpr int TS = 72;
  __shared__ f16 S[12*16*TS];
  __shared__ float gL[12], beL[12];

  int tid = threadIdx.x;
  int w = tid >> 6, lane = tid & 63;
  int kq = lane >> 4, mrow = lane & 15;
  int bx = (blockIdx.x & 7)*512 + (blockIdx.x >> 3);   // XCD-chunked (4096%8==0, bijective)
  int jt = bx & 7, it = (bx >> 3) & 31, b = bx >> 8;
  int i0 = it*16, j0 = jt*64;

  if (tid < 12){ int isb = *flag; gL[tid] = ldf(gamma, tid, isb); beL[tid] = ldf(beta, tid, isb); }

  #pragma unroll
  for (int hh=0; hh<3; hh++){
    int h = w*3 + hh;
    const f16* kb = Kh + ((size_t)(b*12+h)*512 + i0 + mrow)*64;
    h8 a0 = *(const h8*)(kb + kq*8);
    h8 a1 = *(const h8*)(kb + 32 + kq*8);
    const f16* qb = Qh + ((size_t)(b*12+h)*512 + j0)*64;
    #pragma unroll
    for (int jn=0; jn<4; jn++){
      const f16* qr = qb + (size_t)(jn*16 + mrow)*64;
      h8 q0 = *(const h8*)(qr + kq*8);
      h8 q1 = *(const h8*)(qr + 32 + kq*8);
      f32x4 c = (f32x4){0.f,0.f,0.f,0.f};
      c = __builtin_amdgcn_mfma_f32_16x16x32_f16(a0, q0, c, 0, 0, 0);
      c = __builtin_amdgcn_mfma_f32_16x16x32_f16(a1, q1, c, 0, 0, 0);
      #pragma unroll
      for (int r=0;r<4;r++)
        S[(h*16 + kq*4 + r)*TS + jn*16 + mrow] = (f16)c[r];
    }
  }
  __syncthreads();
  int pj = tid & 63, piw = tid >> 6;
  #pragma unroll
  for (int p=0; p<4; p++){
    int i = piw*4 + p;
    float s[12];
    float mu = 0.f, sq = 0.f;
    #pragma unroll
    for (int h=0;h<12;h++){ s[h] = (float)S[(h*16+i)*TS + pj]; mu += s[h]; sq += s[h]*s[h]; }
    mu *= (1.f/12.f);
    float var = fmaxf(sq*(1.f/12.f) - mu*mu, 0.f);
    float rstd = rsqrtf(var + 1e-5f);
    #pragma unroll
    for (int h=0;h<12;h++){
      float e = __expf((s[h]-mu)*rstd*gL[h] + beL[h]);
      S[(h*16+i)*TS + pj] = (f16)e;
    }
  }
  __syncthreads();
  if (tid < 192){
    int h = tid >> 4, i = tid & 15;
    const f16* zr = &S[(h*16 + i)*TS];
    float ssum = 0.f;
    #pragma unroll
    for (int q=0;q<8;q++){
      h8 v = *(const h8*)(zr + q*8);
      #pragma unroll
      for (int t=0;t<8;t++) ssum += (float)v[t];
    }
    lsump[((size_t)(b*12+h)*512 + i0 + i)*8 + jt] = ssum;   // unique owner, plain store
  }
  #pragma unroll
  for (int u0=0; u0<6; u0++){
    int u = tid + u0*256;
    int h = u >> 7, rem = u & 127, i = rem >> 3, q = rem & 7;
    h8 v = *(const h8*)&S[(h*16 + i)*TS + q*8];
    *(h8*)(E + ((size_t)(b*12+h)*512 + i0 + i)*512 + j0 + q*8) = v;
  }
}

// ---------- K3b: PV MFMA from E via LDS-staged contiguous reads; colsum via LDS ----------
__global__ __launch_bounds__(256) void k_pv2(const f16* __restrict__ E,
    const f16* __restrict__ Vt, const float* __restrict__ lsump,
    float* __restrict__ O, float* __restrict__ colsum){
  __shared__ float csL[512];
  __shared__ __align__(16) f16 EL[4*16*256];   // 32 KB: wave w's 16 half-rows (512B each)
  int tid = threadIdx.x;
  int w = tid >> 6, lane = tid & 63;
  int kq = lane >> 4, mrow = lane & 15;
  int b = blockIdx.y;
  int bx = (blockIdx.x & 7)*12 + (blockIdx.x >> 3);     // XCD-chunked (96%8==0, bijective)
  int h = bx >> 3, it = bx & 7;
  int i0w = it*64 + w*16;

  csL[tid] = 0.f; csL[tid + 256] = 0.f;
  const float4* lp = (const float4*)(lsump + ((size_t)(b*12+h)*512 + i0w + mrow)*8);
  float4 p0 = lp[0], p1 = lp[1];
  float rinv = 1.f / (p0.x+p0.y+p0.z+p0.w + p1.x+p1.y+p1.z+p1.w);
  __syncthreads();

  const f16* ebase = E + ((size_t)(b*12+h)*512 + i0w)*512;   // wave's 16 rows
  const f16* vbase = Vt + ((size_t)(b*12+h)*64 + mrow)*512 + kq*8;
  char* Ew = (char*)EL + w*8192;                              // 16 rows x 512B

  f32x4 acc[4];
  #pragma unroll
  for (int nt=0; nt<4; nt++) acc[nt] = (f32x4){0.f,0.f,0.f,0.f};

  for (int ph=0; ph<2; ph++){
    // stage: 8 wave-loads, 2 rows per load (two 512B contiguous segments per instr)
    const f16* eb = ebase + ph*256;
    #pragma unroll
    for (int rr=0; rr<8; rr++){
      int r = rr*2 + (lane>>5);
      h8 v = *(const h8*)(eb + (size_t)r*512 + (lane&31)*8);
      *(h8*)(Ew + r*512 + (((lane&31)*16) ^ ((r&7)<<4))) = v;
    }
    #pragma unroll 4
    for (int jt2=0; jt2<8; jt2++){
      int jt = ph*8 + jt2;
      int j0 = jt*32;
      int co = jt2*64 + kq*16;                              // byte offset in 512B half-row
      h8 ea  = *(const h8*)(Ew + mrow*512 + (co ^ ((mrow&7)<<4)));
      h8 bf0 = *(const h8*)(vbase + j0);
      h8 bf1 = *(const h8*)(vbase + (size_t)16*512 + j0);
      h8 bf2 = *(const h8*)(vbase + (size_t)32*512 + j0);
      h8 bf3 = *(const h8*)(vbase + (size_t)48*512 + j0);
      acc[0] = __builtin_amdgcn_mfma_f32_16x16x32_f16(ea, bf0, acc[0], 0, 0, 0);
      acc[1] = __builtin_amdgcn_mfma_f32_16x16x32_f16(ea, bf1, acc[1], 0, 0, 0);
      acc[2] = __builtin_amdgcn_mfma_f32_16x16x32_f16(ea, bf2, acc[2], 0, 0, 0);
      acc[3] = __builtin_amdgcn_mfma_f32_16x16x32_f16(ea, bf3, acc[3], 0, 0, 0);
      float cs[8];
      #pragma unroll
      for (int t=0;t<8;t++) cs[t] = (float)ea[t] * rinv;
      #pragma unroll
      for (int t=0;t<8;t++){
        cs[t] += __shfl_xor(cs[t], 1); cs[t] += __shfl_xor(cs[t], 2);
        cs[t] += __shfl_xor(cs[t], 4); cs[t] += __shfl_xor(cs[t], 8);
      }
      if (mrow == 0){
        #pragma unroll
        for (int t=0;t<8;t++) atomicAdd(&csL[j0 + kq*8 + t], cs[t]);
      }
    }
  }
  __syncthreads();
  atomicAdd(&colsum[b*512 + tid],       csL[tid]       * (1.f/12.f));
  atomicAdd(&colsum[b*512 + 256 + tid], csL[tid + 256] * (1.f/12.f));

  #pragma unroll
  for (int r=0; r<4; r++){
    float g = __shfl(rinv, kq*4 + r);
    #pragma unroll
    for (int nt=0; nt<4; nt++)
      O[((size_t)(b*512) + i0w + kq*4 + r)*768 + h*64 + nt*16 + mrow] = acc[nt][r] * g;
  }
}

// ---------- K4: merged probs: softmax(O @ Wout^T + bout), branch by blockIdx.y ----------
__global__ __launch_bounds__(256) void k_probs_m(const float* OA, const float* OB,
    const void* WoA, const void* WoB, const void* boA, const void* boB,
    float* prA, float* prB, const int* __restrict__ flag, int sbase){
  int z = sbase + blockIdx.y;
  const float* O = z ? OB : OA;
  const void* Wout = z ? WoB : WoA;
  const void* bout = z ? boB : boA;
  float* probs = z ? prB : prA;
  int isb = *flag;
  int tid = threadIdx.x, wv = tid>>6, lane = tid&63;
  int m = blockIdx.x*4 + wv;
  const float* orow = O + (size_t)m*768;
  float acc[20];
  #pragma unroll
  for (int c=0;c<20;c++) acc[c]=0.f;
  for (int kk=0; kk<12; kk++){
    float o = orow[kk*64 + lane];
    #pragma unroll
    for (int c=0;c<20;c++)
      acc[c] += o * ldf(Wout, c*768 + kk*64 + lane, isb);
  }
  #pragma unroll
  for (int c=0;c<20;c++){
    #pragma unroll
    for (int off=1; off<64; off<<=1) acc[c] += __shfl_xor(acc[c], off, 64);
  }
  float mx = -3.4e38f;
  #pragma unroll
  for (int c=0;c<20;c++){ acc[c] += ldf(bout, c, isb); mx = fmaxf(mx, acc[c]); }
  float s=0.f;
  #pragma unroll
  for (int c=0;c<20;c++){ acc[c] = __expf(acc[c]-mx); s += acc[c]; }
  float inv = 1.f/s;
  if (lane == 0){
    float* pr = probs + (size_t)m*20;
    #pragma unroll
    for (int c=0;c<20;c++) pr[c] = acc[c]*inv;
  }
}

// ---------- K5: merged final: both branches' get_weights + weighted sum + output ----------
__global__ __launch_bounds__(512) void k_final_m(const int* __restrict__ ids,
    const float* __restrict__ cs0, const float* __restrict__ cs1,
    const float* __restrict__ pr0, const float* __restrict__ pr1,
    const int* __restrict__ flag, void* __restrict__ outp){
  __shared__ float red[8];
  __shared__ float bcast;
  __shared__ float pacc[8][20];
  __shared__ float osum[20];
  int b = blockIdx.x, tid = threadIdx.x;
  int wv = tid>>6, lane = tid&63;
  int msk = (ids[b*512+tid] != 0);
  for (int br=0; br<2; br++){
    const float* colsum = br ? cs1 : cs0;
    const float* probs  = br ? pr1 : pr0;
    float w = msk ? colsum[b*512+tid] : 0.f;
    float mx = w;
    #pragma unroll
    for (int off=1; off<64; off<<=1) mx = fmaxf(mx, __shfl_xor(mx, off, 64));
    if (lane==0) red[wv] = mx;
    __syncthreads();
    if (tid==0){ float m2 = red[0]; for (int k2=1;k2<8;k2++) m2 = fmaxf(m2, red[k2]); bcast = m2; }
    __syncthreads();
    float M = bcast;
    float e = __expf(w - M);
    float s = e;
    #pragma unroll
    for (int off=1; off<64; off<<=1) s += __shfl_xor(s, off, 64);
    if (lane==0) red[wv] = s;
    __syncthreads();
    if (tid==0){ float s2=0.f; for (int k2=0;k2<8;k2++) s2 += red[k2]; bcast = s2; }
    __syncthreads();
    float wn = e / bcast;
    float p[20];
    const float* pr = probs + ((size_t)b*512 + tid)*20;
    #pragma unroll
    for (int c=0;c<20;c++) p[c] = wn * pr[c];
    #pragma unroll
    for (int c=0;c<20;c++){
      #pragma unroll
      for (int off=1; off<64; off<<=1) p[c] += __shfl_xor(p[c], off, 64);
    }
    if (lane==0){
      #pragma unroll
      for (int c=0;c<20;c++) pacc[wv][c] = p[c];
    }
    __syncthreads();
    if (tid < 20){
      float s2 = 0.f;
      #pragma unroll
      for (int k2=0;k2<8;k2++) s2 += pacc[k2][tid];
      if (br == 0) osum[tid] = s2;
      else         osum[tid] += s2;
    }
    __syncthreads();
  }
  if (tid < 20){
    float v = osum[tid] * 0.5f;
    if (*flag) ((ushort*)outp)[b*20 + tid] = f2b(v);
    else       ((float*)outp)[b*20 + tid] = v;
  }
}

extern "C" void kernel_launch(void* const* d_in, const int* in_sizes, int n_in,
                              void* d_out, int out_size, void* d_ws, size_t ws_size,
                              hipStream_t stream){
  (void)in_sizes; (void)n_in; (void)out_size;
  const int*  ids = (const int*)d_in[0];
  const void* wvp = d_in[1];
  const void* emb = d_in[2];
  const void* Wt[2]  = {d_in[3], d_in[9]};
  const void* bt[2]  = {d_in[4], d_in[10]};
  const void* gm[2]  = {d_in[5], d_in[11]};
  const void* bet[2] = {d_in[6], d_in[12]};
  const void* Wo[2]  = {d_in[7], d_in[13]};
  const void* bo[2]  = {d_in[8], d_in[14]};

  char* p = (char*)d_ws;
  #define ALLOC(ty, name, cnt) ty* name = (ty*)p; p += sizeof(ty)*(size_t)(cnt)

  // ---- try BIG layout (dual buffers, 9 dispatches) ----
  p = (char*)d_ws;
  ALLOC(float, O0, 6291456);
  ALLOC(float, O1, 6291456);
  ALLOC(f16, Qh0, 6291456); ALLOC(f16, Kh0, 6291456); ALLOC(f16, Vt0, 6291456);
  ALLOC(f16, Qh1, 6291456); ALLOC(f16, Kh1, 6291456); ALLOC(f16, Vt1, 6291456);
  ALLOC(f16, Ah0, 6291456); ALLOC(f16, Wh0, 1769472);
  ALLOC(f16, Ah1, 2621440); ALLOC(f16, Wh1, 737280);
  ALLOC(float, probs0, 163840); ALLOC(float, probs1, 163840);
  ALLOC(float, zb_big, 16384);   // colsum0, colsum1
  ALLOC(int, flag_big, 4);
  ALLOC(f16, E_big, 50331648);
  size_t needBig = (size_t)(p - (char*)d_ws);

  if (ws_size >= needBig){
    float* colsum0 = zb_big;
    float* colsum1 = zb_big + 8192;
    int* flagp = flag_big; f16* E = E_big;
    // rowsum partial buffers alias the A-repack buffer (dead after k_gemm_m)
    float* lsump0 = (float*)Ah0;
    float* lsump1 = lsump0 + 786432;

    k_init<<<65, 256, 0, stream>>>((const ushort*)wvp, flagp, zb_big);
    k_prep_all<<<3072+864+1280+360, 256, 0, stream>>>(ids, emb, wvp, Wt[0], Wt[1],
        flagp, Ah0, Wh0, Ah1, Wh1, 3072, 864, 1280, 360);
    dim3 gg(64, 18, 2);
    k_gemm_m<<<gg, 256, 0, stream>>>(Ah0, Wh0, bt[0], 768, Qh0, Kh0, Vt0,
                                     Ah1, Wh1, bt[1], 320, Qh1, Kh1, Vt1, flagp, 0);
    dim3 gpv(96, 16);
    k_scores<<<4096, 256, 0, stream>>>(Qh0, Kh0, gm[0], bet[0], flagp, E, lsump0);
    k_pv2<<<gpv, 256, 0, stream>>>(E, Vt0, lsump0, O0, colsum0);
    k_scores<<<4096, 256, 0, stream>>>(Qh1, Kh1, gm[1], bet[1], flagp, E, lsump1);
    k_pv2<<<gpv, 256, 0, stream>>>(E, Vt1, lsump1, O1, colsum1);
    dim3 gpr(2048, 2);
    k_probs_m<<<gpr, 256, 0, stream>>>(O0, O1, Wo[0], Wo[1], bo[0], bo[1],
                                       probs0, probs1, flagp, 0);
    k_final_m<<<16, 512, 0, stream>>>(ids, colsum0, colsum1, probs0, probs1, flagp, d_out);
    return;
  }

  // ---- MID layout (shared big buffers, 12 dispatches) ----
  p = (char*)d_ws;
  ALLOC(float, O, 6291456);
  ALLOC(f16, Qh, 6291456); ALLOC(f16, Kh, 6291456); ALLOC(f16, Vt, 6291456);
  ALLOC(f16, Ah, 6291456); ALLOC(f16, Wh, 1769472);
  ALLOC(float, probsA, 163840); ALLOC(float, probsB, 163840);
  ALLOC(float, zb, 16384);
  ALLOC(int, flagm, 4);
  ALLOC(f16, Em, 50331648);
  float* colsum0 = zb;
  float* colsum1 = zb + 8192;
  // rowsum partials alias Ah (dead after each branch's k_gemm_m)
  float* lsumm0 = (float*)Ah;
  float* lsumm1 = lsumm0 + 786432;

  k_init<<<65, 256, 0, stream>>>((const ushort*)wvp, flagm, zb);
  // branch 0
  k_prep_all<<<3072+864, 256, 0, stream>>>(ids, emb, wvp, Wt[0], Wt[1],
      flagm, Ah, Wh, Ah, Wh, 3072, 864, 0, 0);
  dim3 g1(64, 18, 1);
  k_gemm_m<<<g1, 256, 0, stream>>>(Ah, Wh, bt[0], 768, Qh, Kh, Vt,
                                   Ah, Wh, bt[0], 768, Qh, Kh, Vt, flagm, 0);
  dim3 gpv(96, 16);
  k_scores<<<4096, 256, 0, stream>>>(Qh, Kh, gm[0], bet[0], flagm, Em, lsumm0);
  k_pv2<<<gpv, 256, 0, stream>>>(Em, Vt, lsumm0, O, colsum0);
  dim3 gpr(2048, 1);
  k_probs_m<<<gpr, 256, 0, stream>>>(O, O, Wo[0], Wo[1], bo[0], bo[1],
                                     probsA, probsB, flagm, 0);
  // branch 1 (reuse Ah/Wh/QKV/O)
  k_prep_all<<<1280+360, 256, 0, stream>>>(ids, emb, wvp, Wt[0], Wt[1],
      flagm, Ah, Wh, Ah, Wh, 0, 0, 1280, 360);
  k_gemm_m<<<g1, 256, 0, stream>>>(Ah, Wh, bt[1], 320, Qh, Kh, Vt,
                                   Ah, Wh, bt[1], 320, Qh, Kh, Vt, flagm, 0);
  k_scores<<<4096, 256, 0, stream>>>(Qh, Kh, gm[1], bet[1], flagm, Em, lsumm1);
  k_pv2<<<gpv, 256, 0, stream>>>(Em, Vt, lsumm1, O, colsum1);
  k_probs_m<<<gpr, 256, 0, stream>>>(O, O, Wo[0], Wo[1], bo[0], bo[1],
                                     probsA, probsB, flagm, 1);
  k_final_m<<<16, 512, 0, stream>>>(ids, colsum0, colsum1, probsA, probsB, flagm, d_out);
  #undef ALLOC
}